// Round 7
// baseline (1455.056 us; speedup 1.0000x reference)
//
#include <hip/hip_runtime.h>

#define TT 2048
#define FF 12
#define HH 96
#define CH 128
#define SLC 20            // v-slice stride in floats: 16 used + 4 pad -> bank-spread
#define XW  40            // xch row width (2 slices of 20)
#define L2E 1.44269504088896340736f

__device__ __forceinline__ float fast_exp2(float x){ return __builtin_amdgcn_exp2f(x); }
__device__ __forceinline__ float fast_rcp(float x){ return __builtin_amdgcn_rcpf(x); }

// DPP cross-lane at VALU rate. bound_ctrl=true -> OOB lanes read 0.
#define DPPF(x, ctrl) __int_as_float(__builtin_amdgcn_update_dpp(0, __float_as_int(x), (ctrl), 0xF, 0xF, true))
#define QP_XOR1 0xB1   // quad_perm [1,0,3,2]
#define QP_XOR2 0x4E   // quad_perm [2,3,0,1]
#define SHL4    0x104  // row_shl:4 -> dst[i]=src[i+4]
#define SHL8    0x108  // row_shl:8 -> dst[i]=src[i+8]

// One block per batch element (256 blocks = 256 CUs), 512 threads = 8 waves.
// 16-lane group G owns units 3G..3G+2 (12 interleaved gate-rows r'=4u+gate).
// Octet o owns local rows 6o..6o+5; lane cs=lane&7 owns v-cols [16cs,16cs+16)
// (cs<6: h from vv; cs>=6: x from xch). 96 FMA/lane. Reduction over the 8
// col-lanes: row_shl:4 add, then quad_perm xor1/xor2 -> lanes {0-3} hold full
// sums of rows 0-5, lanes {8-11} of rows 6-11. Lane 0 owns ALL gates of unit
// 3G; lane 8 of unit 3G+2; unit 3G+1 completed with TWO row_shl:8 movs.
// LDS read/step: 64B/lane (half of R5) at 20-float slice stride (no >2-way
// bank conflicts). ONE barrier/step; h double-buffered in vv.
// R6->R7 fix: __syncthreads() between prologue init and chunk 0 staging
// (prologue xch zero-init raced with stage-1 writes).
__global__ __launch_bounds__(512, 2) void lstm_persist(
  const float* __restrict__ seq, const int* __restrict__ ev, const int* __restrict__ rsi,
  const int* __restrict__ len, const float* __restrict__ eemb, const float* __restrict__ remb,
  const float* __restrict__ W_ih, const float* __restrict__ W_hh,
  const float* __restrict__ b_ih, const float* __restrict__ b_hh,
  const float* __restrict__ W_mlp, const float* __restrict__ b_mlp,
  const float* __restrict__ W_fc, const float* __restrict__ b_fc,
  float* __restrict__ out)
{
  const int b   = blockIdx.x;
  const int tid = threadIdx.x;
  const int G   = tid >> 4;     // 16-lane group, 0..31
  const int lu  = tid & 15;     // lane in group
  const int oct = lu >> 3;      // octet in group
  const int cs  = lu & 7;       // col-slice in octet

  __shared__ __align__(16) float vv[2][8*SLC];  // double-buffered h in 20-float slices
  __shared__ __align__(16) float xch[CH][XW];   // staged x: [0..16)=x0..15, [20..25)=x16..20, rest 0
  __shared__ __align__(16) float lastk[3*HH];
  __shared__ __align__(16) float et[192];
  __shared__ __align__(16) float rt[24];
  __shared__ __align__(16) float accs[192];
  __shared__ __align__(16) float h2[192];
  __shared__ int evb[CH];
  __shared__ int rsb[CH];

  // ---- prologue: 6 rows x 16 cols of weights per lane ----
  float wh[6][16], bg[6], cK[6], cM[6], cB[6];
  #pragma unroll
  for (int j = 0; j < 6; ++j) {
    const int lr   = 6*oct + j;          // local row 0..11
    const int u_   = 3*G + (lr >> 2);
    const int gate = lr & 3;             // 0=i 1=f 2=g 3=o
    const int grow = gate*96 + u_;
    #pragma unroll
    for (int i = 0; i < 16; ++i) {
      const int col = 16*cs + i;         // v-col: [0,96) h, [96,117) x, else pad
      wh[j][i] = (col < 96) ? W_hh[grow*96 + col]
               : ((col < 117) ? W_ih[grow*21 + (col-96)] : 0.f);
    }
    bg[j] = (cs == 0) ? (b_ih[grow] + b_hh[grow]) : 0.f;
    const bool t = (gate == 2);
    cK[j] = t ? (-2.f*L2E) : (-L2E);     // sigmoid: 1/(1+2^(-z*log2e)); tanh: 2*sig(2s)-1
    cM[j] = t ? 2.f : 1.f;
    cB[j] = t ? -1.f : 0.f;
  }
  const int un = 3*G + ((lu == 8) ? 2 : lu);   // update-lane unit (lu in {0,1,8})

  for (int i = tid; i < 2*8*SLC; i += 512) ((float*)vv)[i]  = 0.f;
  for (int i = tid; i < CH*XW;   i += 512) ((float*)xch)[i] = 0.f;  // pads stay 0 forever
  for (int i = tid; i < 3*HH;    i += 512) lastk[i] = 0.f;
  if (tid < 192) et[tid] = eemb[tid];
  if (tid < 24)  rt[tid] = remb[tid];
  __syncthreads();                       // init must drain before chunk-0 staging

  float c_state = 0.f;
  const int L = len[b];                  // state frozen past L; outputs past L unused

  for (int t0 = 0; t0 < L; t0 += CH) {
    // ---- stage 1: coalesced seq load (cols 0..11) + indices ----
    for (int i = tid; i < CH*FF; i += 512) {
      const int r = i / 12, c = i - r*12;
      xch[r][c] = seq[(size_t)b*(TT*FF) + (size_t)t0*FF + i];
    }
    if (tid < CH) {
      evb[tid] = ev [b*TT + t0 + tid];
      rsb[tid] = rsi[b*TT + t0 + tid];
    }
    __syncthreads();
    // ---- stage 2: embedding gather into x-cols 12..20 (split layout) ----
    for (int i = tid; i < CH*9; i += 512) {
      const int r = i / 9, c = 12 + (i - r*9);
      const float val = (c < 18) ? et[evb[r]*6 + (c-12)] : rt[rsb[r]*3 + (c-18)];
      xch[r][(c < 16) ? c : (c + 4)] = val;   // cols>=16 live at [20..25)
    }
    __syncthreads();

    const int nr = min(CH, L - t0);
    for (int r = 0; r < nr; ++r) {
      const int p = (t0 + r) & 1;
      // ---- slice read: 4x ds_read_b128, 64B/lane ----
      const float* vp = (cs < 6) ? (vv[p] + SLC*cs) : (&xch[r][(cs-6)*SLC]);
      float hb[16];
      #pragma unroll
      for (int i = 0; i < 4; ++i) *(float4*)&hb[4*i] = ((const float4*)vp)[i];

      // ---- 6 rows x 16-col partials ----
      float S[6];
      #pragma unroll
      for (int j = 0; j < 6; ++j) {
        float a0 = bg[j], a1 = 0.f;
        #pragma unroll
        for (int i = 0; i < 8; ++i) {
          a0 = fmaf(wh[j][2*i],   hb[2*i],   a0);
          a1 = fmaf(wh[j][2*i+1], hb[2*i+1], a1);
        }
        S[j] = a0 + a1;
      }
      // ---- 8-lane reduce: shl4 (octet fold) + quad butterfly ----
      #pragma unroll
      for (int j = 0; j < 6; ++j) S[j] += DPPF(S[j], SHL4);
      #pragma unroll
      for (int j = 0; j < 6; ++j) S[j] += DPPF(S[j], QP_XOR1);
      #pragma unroll
      for (int j = 0; j < 6; ++j) S[j] += DPPF(S[j], QP_XOR2);
      // ---- branchless activations (4 instr each) ----
      float A[6];
      #pragma unroll
      for (int j = 0; j < 6; ++j) {
        const float e = fast_exp2(cK[j]*S[j]);
        A[j] = fmaf(cM[j], fast_rcp(1.f + e), cB[j]);
      }
      // ---- cross-octet: unit 3G+1's g,o (rows 6,7) to lanes 0-7 ----
      const float X0 = DPPF(A[0], SHL8);
      const float X1 = DPPF(A[1], SHL8);
      // ---- unit update: lanes 0 (unit 3G), 1 (3G+1), 8 (3G+2) ----
      if ((lu == 0) | (lu == 1) | (lu == 8)) {
        const float i_ = (lu==1) ? A[4] : ((lu==8) ? A[2] : A[0]);
        const float f_ = (lu==1) ? A[5] : ((lu==8) ? A[3] : A[1]);
        const float g_ = (lu==1) ? X0   : ((lu==8) ? A[4] : A[2]);
        const float o_ = (lu==1) ? X1   : ((lu==8) ? A[5] : A[3]);
        c_state = fmaf(f_, c_state, i_*g_);
        const float e2 = fast_exp2((-2.f*L2E)*fabsf(c_state));
        const float th = copysignf((1.f - e2)*fast_rcp(1.f + e2), c_state);
        const float hn = o_ * th;
        vv[p^1][SLC*(un >> 4) + (un & 15)] = hn;
        const int kk = (t0 + r) + 3 - L;         // last-K ring: t in [L-3, L)
        if (kk >= 0) lastk[kk*96 + un] = hn;
      }
      __syncthreads();
    }
  }

  // ---- epilogue: h_fin from vv[L&1]; h_lastk = relu(W_mlp@lastk+b); out = W_fc@[h|h_lastk]+b ----
  if (tid < 192) {
    const int hh = tid / 96;
    const int m  = tid - hh*96;
    const float* wp = W_mlp + m*288 + hh*144;
    const float* xq = lastk + hh*144;
    float s = 0.f;
    #pragma unroll 8
    for (int i = 0; i < 144; ++i) s = fmaf(wp[i], xq[i], s);
    accs[tid] = s;
  }
  __syncthreads();
  if (tid < 96) {
    const float hl = accs[tid] + accs[96+tid] + b_mlp[tid];
    h2[96 + tid] = fmaxf(hl, 0.f);
    h2[tid] = vv[L & 1][SLC*(tid >> 4) + (tid & 15)];
  }
  __syncthreads();
  if (tid < 128) {
    const int o  = tid >> 6;
    const int ll = tid & 63;
    const float* wf = W_fc + o*192 + 3*ll;
    float s = fmaf(wf[0], h2[3*ll+0], fmaf(wf[1], h2[3*ll+1], wf[2]*h2[3*ll+2]));
    #pragma unroll
    for (int off = 32; off > 0; off >>= 1) s += __shfl_down(s, off);
    if (ll == 0) out[b*2 + o] = s + b_fc[o];
  }
}

extern "C" void kernel_launch(void* const* d_in, const int* in_sizes, int n_in,
                              void* d_out, int out_size, void* d_ws, size_t ws_size,
                              hipStream_t stream) {
  const float* seq   = (const float*)d_in[0];
  const int*   ev    = (const int*)  d_in[1];
  const int*   rsi   = (const int*)  d_in[2];
  const int*   len   = (const int*)  d_in[3];
  const float* eemb  = (const float*)d_in[4];
  const float* remb  = (const float*)d_in[5];
  const float* W_ih  = (const float*)d_in[6];
  const float* W_hh  = (const float*)d_in[7];
  const float* b_ih  = (const float*)d_in[8];
  const float* b_hh  = (const float*)d_in[9];
  const float* W_mlp = (const float*)d_in[10];
  const float* b_mlp = (const float*)d_in[11];
  const float* W_fc  = (const float*)d_in[12];
  const float* b_fc  = (const float*)d_in[13];

  hipLaunchKernelGGL(lstm_persist, dim3(256), dim3(512), 0, stream,
                     seq, ev, rsi, len, eemb, remb, W_ih, W_hh, b_ih, b_hh,
                     W_mlp, b_mlp, W_fc, b_fc, (float*)d_out);
}